// Round 3
// baseline (115.395 us; speedup 1.0000x reference)
//
#include <hip/hip_runtime.h>

// INRF: out[b,ij,c] = first - second
//   first  = sum_pq M2[ij,pq] * x[b,pq,c]                  (phase1, fp32, writes out)
//   second = sum_pq W2[ij,pq] * relu(x[b,pq,c] - S)        (main, MFMA bf16 GEMM for S)
//   S[b,pq,ij,f] = sum_k patch(x)[b,pq,k] * G[ij,k,f], K=144 (3x3x16), padded to 160.
// A (im2col patches, bf16, MFMA-frag-swizzled) lives in d_ws.

typedef __attribute__((ext_vector_type(8))) short bf16x8;
typedef __attribute__((ext_vector_type(4))) float f32x4;

__device__ inline unsigned short f2bf(float x) {
    unsigned u = __float_as_uint(x);
    u += 0x7FFFu + ((u >> 16) & 1u);
    return (unsigned short)(u >> 16);
}
__device__ inline unsigned pack2(float a, float b) {
    return (unsigned)f2bf(a) | ((unsigned)f2bf(b) << 16);
}

// ---------- Phase 1: blocks 0..143 im2col taps, 144..159 K-pad, 160..415 "first" ----------
__global__ __launch_bounds__(256) void inrf_phase1(
    const float* __restrict__ inp, const float* __restrict__ M,
    uint4* __restrict__ A, float* __restrict__ out)
{
    const int bb = blockIdx.x, t = threadIdx.x;

    if (bb < 144) {                       // one thread per (row, tap)
        const int gid = bb * 256 + t;     // 0..36863
        const int row = gid / 9, tap = gid - row * 9;
        const int b = row >> 10, pq = row & 1023, p = pq >> 5, q = pq & 31;
        const int tile = row >> 4, m = row & 15;
        const int dh = tap / 3, dw = tap - dh * 3;
        const int pp = p + dh - 1, qq = q + dw - 1;
        const bool v = ((unsigned)pp < 32u) && ((unsigned)qq < 32u);
        uint4 lo = {0, 0, 0, 0}, hi = {0, 0, 0, 0};
        if (v) {
            const float4* s = (const float4*)(inp + b * 16384 + (pp * 32 + qq) * 16);
            float4 f0 = s[0], f1 = s[1], f2 = s[2], f3 = s[3];
            lo.x = pack2(f0.x, f0.y); lo.y = pack2(f0.z, f0.w);
            lo.z = pack2(f1.x, f1.y); lo.w = pack2(f1.z, f1.w);
            hi.x = pack2(f2.x, f2.y); hi.y = pack2(f2.z, f2.w);
            hi.z = pack2(f3.x, f3.y); hi.w = pack2(f3.z, f3.w);
        }
        const int kk = tap >> 1, qa = (tap & 1) * 2;
        const int base = (tile * 5 + kk) * 64 + qa * 16 + m;
        A[base] = lo;
        A[base + 16] = hi;
        return;
    }
    if (bb < 160) {                       // zero-pad k=144..159 (kk=4, quads 2,3)
        const int row = (bb - 144) * 256 + t;   // 0..4095
        const int tile = row >> 4, m = row & 15;
        const uint4 z = {0, 0, 0, 0};
        const int base = (tile * 5 + 4) * 64 + 32 + m;
        A[base] = z;
        A[base + 16] = z;
        return;
    }

    // "first": out[b, ij, c] = sum_pq M2[ij,pq] * x[b,pq,c]  (4 ij per block)
    __shared__ float M2l[4096];
    __shared__ float4 red2[256];
    const int g = bb - 160;               // 0..255
    for (int i = t; i < 4096; i += 256) M2l[i] = M[g * 4096 + i];
    __syncthreads();

    const int chunk = t >> 6, rest = t & 63;
    const int ijl = rest >> 4, b = (rest >> 2) & 3, cg = t & 3;
    const float4* xb = (const float4*)(inp + b * 16384) + cg;
    const float4* mrow = (const float4*)&M2l[ijl * 1024 + chunk * 256];
    float4 s = {0.f, 0.f, 0.f, 0.f};
    const int pq0 = chunk * 256;
    for (int r = 0; r < 256; r += 4) {
        const float4 mm = mrow[r >> 2];
        const float4 x0 = xb[(pq0 + r + 0) * 4];
        const float4 x1 = xb[(pq0 + r + 1) * 4];
        const float4 x2 = xb[(pq0 + r + 2) * 4];
        const float4 x3 = xb[(pq0 + r + 3) * 4];
        s.x += mm.x * x0.x + mm.y * x1.x + mm.z * x2.x + mm.w * x3.x;
        s.y += mm.x * x0.y + mm.y * x1.y + mm.z * x2.y + mm.w * x3.y;
        s.z += mm.x * x0.z + mm.y * x1.z + mm.z * x2.z + mm.w * x3.z;
        s.w += mm.x * x0.w + mm.y * x1.w + mm.z * x2.w + mm.w * x3.w;
    }
    red2[t] = s;
    __syncthreads();
    if (t < 64) {
        const float4 a = red2[t], b4 = red2[t + 64], c4 = red2[t + 128], d4 = red2[t + 192];
        float4 r;
        r.x = (a.x + b4.x) + (c4.x + d4.x);
        r.y = (a.y + b4.y) + (c4.y + d4.y);
        r.z = (a.z + b4.z) + (c4.z + d4.z);
        r.w = (a.w + b4.w) + (c4.w + d4.w);
        const int oij = t >> 4, ob = (t >> 2) & 3, ocg = t & 3;
        *(float4*)(out + ob * 16384 + (g * 4 + oij) * 16 + ocg * 4) = r;
    }
}

// ---------- Main: grid 1024 (g=bid&255 ij-group, b=bid>>8), 256 thr = 4 waves ----------
__global__ __launch_bounds__(256, 2) void inrf_main(
    const float* __restrict__ inp, const float* __restrict__ Wp,
    const float* __restrict__ G, const uint4* __restrict__ Aw,
    float* __restrict__ out)
{
    const int bid = blockIdx.x;
    const int g = bid & 255, b = bid >> 8;
    const int t = threadIdx.x;

    __shared__ __align__(16) float W2l[4096];
    __shared__ __align__(16) float G_l[9216];
    __shared__ float red[4][64];

    for (int i = t; i < 4096; i += 256) W2l[i] = Wp[g * 4096 + i];
    for (int i = t; i < 9216; i += 256) G_l[i] = G[g * 9216 + i];
    __syncthreads();

    const int w = t >> 6, l = t & 63, quad = l >> 4, col = l & 15;

    // B fragments: lane holds G[k = kk*32 + quad*8 + j][f = col], bf16
    bf16x8 Bf[4][5];
#pragma unroll
    for (int ij = 0; ij < 4; ++ij)
#pragma unroll
        for (int kk = 0; kk < 5; ++kk) {
            bf16x8 f;
#pragma unroll
            for (int j = 0; j < 8; ++j) {
                const int k = kk * 32 + quad * 8 + j;
                const float v = (k < 144) ? G_l[ij * 2304 + k * 16 + col] : 0.f;
                f[j] = (short)f2bf(v);
            }
            Bf[ij][kk] = f;
        }

    const float* inb = inp + b * 16384;
    const int tile0 = b * 64 + w * 16;        // 16 tiles per wave
    float accv[4] = {0.f, 0.f, 0.f, 0.f};

    uint4 Acur[5], Anxt[5];
    float vcur[4], vnxt[4];
    {
#pragma unroll
        for (int kk = 0; kk < 5; ++kk) Acur[kk] = Aw[(tile0 * 5 + kk) * 64 + l];
        const int pqb = (tile0 & 63) * 16 + quad * 4;
#pragma unroll
        for (int r = 0; r < 4; ++r) vcur[r] = inb[(pqb + r) * 16 + col];
    }

    for (int i = 0; i < 16; ++i) {
        const int tg = tile0 + i;
        if (i < 15) {
            const int tn = tg + 1;
#pragma unroll
            for (int kk = 0; kk < 5; ++kk) Anxt[kk] = Aw[(tn * 5 + kk) * 64 + l];
            const int pqb = (tn & 63) * 16 + quad * 4;
#pragma unroll
            for (int r = 0; r < 4; ++r) vnxt[r] = inb[(pqb + r) * 16 + col];
        }

        f32x4 C[4];
#pragma unroll
        for (int ij = 0; ij < 4; ++ij) C[ij] = (f32x4){0.f, 0.f, 0.f, 0.f};
#pragma unroll
        for (int kk = 0; kk < 5; ++kk) {
            const bf16x8 a = __builtin_bit_cast(bf16x8, Acur[kk]);
#pragma unroll
            for (int ij = 0; ij < 4; ++ij)
                C[ij] = __builtin_amdgcn_mfma_f32_16x16x32_bf16(a, Bf[ij][kk], C[ij], 0, 0, 0);
        }

        const int pqb = (tg & 63) * 16 + quad * 4;
#pragma unroll
        for (int ij = 0; ij < 4; ++ij) {
            const float4 w2 = *(const float4*)&W2l[ij * 1024 + pqb];
            accv[ij] += w2.x * fmaxf(vcur[0] - C[ij][0], 0.f)
                      + w2.y * fmaxf(vcur[1] - C[ij][1], 0.f)
                      + w2.z * fmaxf(vcur[2] - C[ij][2], 0.f)
                      + w2.w * fmaxf(vcur[3] - C[ij][3], 0.f);
        }

#pragma unroll
        for (int kk = 0; kk < 5; ++kk) Acur[kk] = Anxt[kk];
#pragma unroll
        for (int r = 0; r < 4; ++r) vcur[r] = vnxt[r];
    }

    // reduce over quads; lanes 0..15 end with the full column sum
#pragma unroll
    for (int ij = 0; ij < 4; ++ij) {
        float v = accv[ij];
        v += __shfl_xor(v, 16);
        v += __shfl_xor(v, 32);
        if (l < 16) red[w][ij * 16 + l] = v;
    }
    __syncthreads();

    if (t < 64) {
        const int oij = t >> 4, oc = t & 15;
        const float sec = red[0][t] + red[1][t] + red[2][t] + red[3][t];
        out[b * 16384 + (g * 4 + oij) * 16 + oc] -= sec;   // out held "first"; L = 1
    }
}

extern "C" void kernel_launch(void* const* d_in, const int* in_sizes, int n_in,
                              void* d_out, int out_size, void* d_ws, size_t ws_size,
                              hipStream_t stream) {
    const float* inp = (const float*)d_in[0];
    const float* M   = (const float*)d_in[1];
    const float* Wp  = (const float*)d_in[2];
    const float* G   = (const float*)d_in[3];
    float* out = (float*)d_out;

    uint4* A = (uint4*)d_ws;                 // 4096*160*2B = 1.31 MB
    inrf_phase1<<<dim3(416), dim3(256), 0, stream>>>(inp, M, A, out);
    inrf_main<<<dim3(1024), dim3(256), 0, stream>>>(inp, Wp, G, A, out);
}

// Round 5
// 105.262 us; speedup vs baseline: 1.0963x; 1.0963x over previous
//
#include <hip/hip_runtime.h>

// INRF, single self-contained kernel (no d_ws, no inter-kernel state):
//   out[b,ij,c] = sum_pq [ M2[ij,pq]*x[b,pq,c] - W2[ij,pq]*relu(x[b,pq,c] - S[b,pq,ij,c]) ]
//   S[b,pq,ij,f] = sum_k patch(x)[b,pq,k] * G[ij,k,f],  K=144 (3x3x16) padded to 160.
// Per block (g -> 4 ij, b): LDS 34x34 halo bf16 image (XOR-swizzled halves, conflict-free
// ds_read_b128 A-frags, halo = free zero padding), LDS G-transpose for one-time B-frag
// build, 20 MFMA 16x16x32_bf16 per K-step, fp32 epilogue with global W2/M2/x.

typedef __attribute__((ext_vector_type(8))) short bf16x8;
typedef __attribute__((ext_vector_type(4))) float f32x4;

__device__ inline unsigned short f2bf(float x) {
    unsigned u = __float_as_uint(x);
    u += 0x7FFFu + ((u >> 16) & 1u);     // round-to-nearest-even
    return (unsigned short)(u >> 16);
}
__device__ inline unsigned pack2(float a, float b) {
    return (unsigned)f2bf(a) | ((unsigned)f2bf(b) << 16);
}

__global__ __launch_bounds__(256, 2) void inrf_fused(
    const float* __restrict__ inp,   // (4,1024,16)
    const float* __restrict__ M,     // 4096 per 4-ij group
    const float* __restrict__ Wp,    // 4096 per 4-ij group
    const float* __restrict__ G,     // 9216 per 4-ij group
    float* __restrict__ out)         // (4,1024,16)
{
    const int bid = blockIdx.x;
    const int g = bid >> 2, b = bid & 3;
    const int t = threadIdx.x, w = t >> 6, l = t & 63;
    const int quad = l >> 4, m = l & 15;      // m = A-row within tile = output col index
    const int half = quad & 1;

    // Xl: 34x34 cells x 32B (16 bf16 ch). Cell hc, 16B-half s stored at uint4
    // index 2*hc + (s ^ (hc&1))  -> quad-stride reads are 2-way (free).
    __shared__ __align__(16) uint4 Xl[1156 * 2];          // 36992 B
    __shared__ __align__(16) short Gt[4 * 16 * 168];      // [ij][f][k] bf16, 21504 B
    __shared__ float red[4][64];

    // ---- stage: zero Xl (halo incl.), Gt pad zeros, Gt real values ----
    for (int i = t; i < 2312; i += 256) Xl[i] = (uint4){0, 0, 0, 0};
    for (int i = t; i < 1536; i += 256) {                 // k = 144..167 pad
        const int ij = i / 384, r2 = i - ij * 384;
        const int cf = r2 / 24, kp = r2 - cf * 24;
        Gt[(ij * 16 + cf) * 168 + 144 + kp] = 0;
    }
    for (int i = t; i < 9216; i += 256) {                 // transpose G -> Gt bf16
        const int ij = i / 2304, r2 = i - ij * 2304;
        const int k = r2 >> 4, cf = r2 & 15;
        Gt[(ij * 16 + cf) * 168 + k] = (short)f2bf(G[g * 9216 + i]);
    }
    __syncthreads();

    // ---- fill Xl interior (overwrites zeroed interior cells) ----
    {
        const float4* xb = (const float4*)(inp + b * 16384);
        for (int r = t; r < 1024; r += 256) {
            const int p = r >> 5, q = r & 31;
            const int hc = (p + 1) * 34 + (q + 1);
            const float4 f0 = xb[r * 4 + 0], f1 = xb[r * 4 + 1];
            const float4 f2 = xb[r * 4 + 2], f3 = xb[r * 4 + 3];
            uint4 lo, hi;
            lo.x = pack2(f0.x, f0.y); lo.y = pack2(f0.z, f0.w);
            lo.z = pack2(f1.x, f1.y); lo.w = pack2(f1.z, f1.w);
            hi.x = pack2(f2.x, f2.y); hi.y = pack2(f2.z, f2.w);
            hi.z = pack2(f3.x, f3.y); hi.w = pack2(f3.z, f3.w);
            const int sw = hc & 1;
            Xl[2 * hc + sw] = lo;          // half 0
            Xl[2 * hc + (sw ^ 1)] = hi;    // half 1
        }
    }

    // ---- B fragments from Gt (one-time; Gt was complete before the barrier) ----
    bf16x8 Bf[4][5];
#pragma unroll
    for (int ij = 0; ij < 4; ++ij)
#pragma unroll
        for (int kk = 0; kk < 5; ++kk)
            Bf[ij][kk] = *(const bf16x8*)&Gt[(ij * 16 + m) * 168 + kk * 32 + quad * 8];

    // ---- per-lane A-frag address constants ----
    // frag kk covers k = kk*32 + quad*8 + j  ->  tap = 2kk + (quad>>1), channels half*8..+7
    int K_[5];
#pragma unroll
    for (int kk = 0; kk < 5; ++kk) {
        const int tap = 2 * kk + (quad >> 1);             // 0..9 (9 => zero pad)
        const int dh = tap / 3, dw = tap - dh * 3;
        K_[kk] = (dh * 34 + dw) * 32 + ((half ^ (dw & 1)) << 4);
    }
    __syncthreads();

    const int tile0w = w * 16;                 // local tile index within batch b
    const float* wrow = Wp + g * 4096;
    const float* mrow = M + g * 4096;
    const float* xrow = inp + b * 16384 + m;   // + (pq)*16

    auto loadA = [&](int i, uint4* dst) {
        const int pq = (tile0w + i) * 16 + m;
        const int p = pq >> 5, q = pq & 31;
        const int base = (p * 34 + q) * 32;
        const int qo = (q & 1) << 4;
#pragma unroll
        for (int kk = 0; kk < 5; ++kk) {
            int a = (base + K_[kk]) ^ qo;
            if (kk == 4) a = (quad >= 2) ? 0 : a;         // cell 0 = halo zero
            dst[kk] = *(const uint4*)((const char*)Xl + a);
        }
    };

    float accv[4] = {0.f, 0.f, 0.f, 0.f};
    uint4 Acur[5], Anxt[5];
    loadA(0, Acur);

    for (int i = 0; i < 16; ++i) {
        const int pqb = (tile0w + i) * 16 + quad * 4;

        // issue W2/M2/x loads now; consumed after the MFMA block (~160-cycle shadow)
        float4 w2[4], m2[4];
        float xv[4];
#pragma unroll
        for (int ij = 0; ij < 4; ++ij) {
            w2[ij] = *(const float4*)&wrow[ij * 1024 + pqb];
            m2[ij] = *(const float4*)&mrow[ij * 1024 + pqb];
        }
#pragma unroll
        for (int r = 0; r < 4; ++r) xv[r] = xrow[(pqb + r) * 16];

        if (i < 15) loadA(i + 1, Anxt);

        f32x4 C[4];
#pragma unroll
        for (int ij = 0; ij < 4; ++ij) C[ij] = (f32x4){0.f, 0.f, 0.f, 0.f};
#pragma unroll
        for (int kk = 0; kk < 5; ++kk) {
            const bf16x8 a = __builtin_bit_cast(bf16x8, Acur[kk]);
#pragma unroll
            for (int ij = 0; ij < 4; ++ij)
                C[ij] = __builtin_amdgcn_mfma_f32_16x16x32_bf16(a, Bf[ij][kk], C[ij], 0, 0, 0);
        }

        // fused epilogue: acc += M2*x - W2*relu(x - S);  C row r ↔ pq = pqb + r, col = m
#pragma unroll
        for (int ij = 0; ij < 4; ++ij) {
            accv[ij] += m2[ij].x * xv[0] - w2[ij].x * fmaxf(xv[0] - C[ij][0], 0.f);
            accv[ij] += m2[ij].y * xv[1] - w2[ij].y * fmaxf(xv[1] - C[ij][1], 0.f);
            accv[ij] += m2[ij].z * xv[2] - w2[ij].z * fmaxf(xv[2] - C[ij][2], 0.f);
            accv[ij] += m2[ij].w * xv[3] - w2[ij].w * fmaxf(xv[3] - C[ij][3], 0.f);
        }

#pragma unroll
        for (int kk = 0; kk < 5; ++kk) Acur[kk] = Anxt[kk];
    }

    // reduce over quads; lanes 0..15 hold full column sums for this wave's tiles
#pragma unroll
    for (int ij = 0; ij < 4; ++ij) {
        float v = accv[ij];
        v += __shfl_xor(v, 16);
        v += __shfl_xor(v, 32);
        if (l < 16) red[w][ij * 16 + l] = v;
    }
    __syncthreads();

    if (t < 64) {
        const int oij = t >> 4, oc = t & 15;
        const float r0 = red[0][t] + red[1][t] + red[2][t] + red[3][t];
        out[b * 16384 + (g * 4 + oij) * 16 + oc] = r0;    // L = 1
    }
}

extern "C" void kernel_launch(void* const* d_in, const int* in_sizes, int n_in,
                              void* d_out, int out_size, void* d_ws, size_t ws_size,
                              hipStream_t stream) {
    const float* inp = (const float*)d_in[0];
    const float* M   = (const float*)d_in[1];
    const float* Wp  = (const float*)d_in[2];
    const float* G   = (const float*)d_in[3];
    float* out = (float*)d_out;

    inrf_fused<<<dim3(1024), dim3(256), 0, stream>>>(inp, M, Wp, G, out);
}